// Round 1
// baseline (494.597 us; speedup 1.0000x reference)
//
#include <hip/hip_runtime.h>
#include <cstdint>
#include <cstddef>

typedef float   f32x4 __attribute__((ext_vector_type(4)));
typedef _Float16 f16x8 __attribute__((ext_vector_type(8)));
typedef _Float16 f16x4 __attribute__((ext_vector_type(4)));

#define TOK  4096   // B*S tokens
#define HID  1024
#define IDIM 4096

// ---------------------------------------------------------------------------
// GEMM: C[M x Ncols] = A[M x K] * B[Ncols x K]^T   (NT form, fp16 MFMA, fp32 acc)
// 128x128 tile, BK=32, 256 threads = 4 waves in 2x2, each wave 64x64 (4x4 MFMA).
// MODE 0: outF = acc + bias[n]                         (dense -> h)
// MODE 1: outH = f16(acc + (bias?bias[n]:0))           (query / qk / g)
// MODE 2: outH = f16(relu(acc + bias[n]))              (down)
// MODE 3: outH = f16(acc + addv + sum_t probs*up_b)    (mixed)
// MODE 4: outF = acc + addv                            (value + input_tensor)
// ---------------------------------------------------------------------------
template <int MODE, bool AF32>
__global__ __launch_bounds__(256) void gemm_nt(
    const float* __restrict__ Af, const _Float16* __restrict__ Ah,
    const _Float16* __restrict__ B, int K, int Ncols,
    float* __restrict__ outF, _Float16* __restrict__ outH,
    const float* __restrict__ bias, const float* __restrict__ addv,
    const float* __restrict__ probs, const float* __restrict__ upb)
{
    __shared__ _Float16 lA[128 * 32];
    __shared__ _Float16 lB[128 * 32];
    const int tid  = threadIdx.x;
    const int lane = tid & 63;
    const int wave = tid >> 6;
    const int m0   = blockIdx.x * 128;
    const int n0   = blockIdx.y * 128;
    const int wM   = (wave & 1) * 64;
    const int wN   = (wave >> 1) * 64;

    f32x4 acc[4][4] = {};

    for (int k0 = 0; k0 < K; k0 += 32) {
#pragma unroll
        for (int j = 0; j < 2; ++j) {
            const int q   = tid + j * 256;   // 512 chunks of 16B per 128x32 tile
            const int row = q >> 2;
            const int kc  = q & 3;
            if constexpr (AF32) {
                const float* src = Af + (size_t)(m0 + row) * K + k0 + kc * 8;
                f32x4 v0 = *(const f32x4*)src;
                f32x4 v1 = *(const f32x4*)(src + 4);
                f16x8 o;
                o[0] = (_Float16)v0[0]; o[1] = (_Float16)v0[1];
                o[2] = (_Float16)v0[2]; o[3] = (_Float16)v0[3];
                o[4] = (_Float16)v1[0]; o[5] = (_Float16)v1[1];
                o[6] = (_Float16)v1[2]; o[7] = (_Float16)v1[3];
                *(f16x8*)(lA + row * 32 + kc * 8) = o;
            } else {
                uint4 v = *(const uint4*)(Ah + (size_t)(m0 + row) * K + k0 + kc * 8);
                *(uint4*)(lA + row * 32 + kc * 8) = v;
            }
            uint4 vb = *(const uint4*)(B + (size_t)(n0 + row) * K + k0 + kc * 8);
            *(uint4*)(lB + row * 32 + kc * 8) = vb;
        }
        __syncthreads();
        const int fr  = lane & 15;
        const int kc8 = (lane >> 4) * 8;
        f16x8 afr[4], bfr[4];
#pragma unroll
        for (int mi = 0; mi < 4; ++mi)
            afr[mi] = *(const f16x8*)(lA + (wM + mi * 16 + fr) * 32 + kc8);
#pragma unroll
        for (int ni = 0; ni < 4; ++ni)
            bfr[ni] = *(const f16x8*)(lB + (wN + ni * 16 + fr) * 32 + kc8);
#pragma unroll
        for (int mi = 0; mi < 4; ++mi)
#pragma unroll
            for (int ni = 0; ni < 4; ++ni)
                acc[mi][ni] = __builtin_amdgcn_mfma_f32_16x16x32_f16(
                    afr[mi], bfr[ni], acc[mi][ni], 0, 0, 0);
        __syncthreads();
    }

    // epilogue: C/D layout col = lane&15, row = (lane>>4)*4 + reg
    const int cn = lane & 15;
    const int rq = (lane >> 4) * 4;
#pragma unroll
    for (int mi = 0; mi < 4; ++mi) {
#pragma unroll
        for (int r = 0; r < 4; ++r) {
            const int m = m0 + wM + mi * 16 + rq + r;
#pragma unroll
            for (int ni = 0; ni < 4; ++ni) {
                const int n = n0 + wN + ni * 16 + cn;
                const size_t idx = (size_t)m * Ncols + n;
                const float v = acc[mi][ni][r];
                if constexpr (MODE == 0) {
                    outF[idx] = v + bias[n];
                } else if constexpr (MODE == 1) {
                    const float bb = bias ? bias[n] : 0.f;
                    outH[idx] = (_Float16)(v + bb);
                } else if constexpr (MODE == 2) {
                    const float y = v + bias[n];
                    outH[idx] = (_Float16)(y > 0.f ? y : 0.f);
                } else if constexpr (MODE == 3) {
                    float s = v + addv[idx];
#pragma unroll
                    for (int t = 0; t < 8; ++t)
                        s += probs[(size_t)m * 8 + t] * upb[t * 1024 + n];
                    outH[idx] = (_Float16)s;
                } else {
                    outF[idx] = v + addv[idx];
                }
            }
        }
    }
}

// ---------------------------------------------------------------------------
// LN over prenorm = h + input_tensor; emits adapter_in (f16) and prenorm (f16)
// ---------------------------------------------------------------------------
__global__ __launch_bounds__(256) void ln_adapter(
    const float* __restrict__ hbuf, const float* __restrict__ it,
    const float* __restrict__ gam, const float* __restrict__ bet,
    _Float16* __restrict__ ai, _Float16* __restrict__ pn)
{
    const int n = blockIdx.x, tid = threadIdx.x;
    const int lane = tid & 63, wave = tid >> 6;
    const size_t base = (size_t)n * 1024 + tid * 4;
    f32x4 hv = *(const f32x4*)(hbuf + base);
    f32x4 iv = *(const f32x4*)(it + base);
    f32x4 x = hv + iv;
    float s = x[0] + x[1] + x[2] + x[3];
    float q = x[0] * x[0] + x[1] * x[1] + x[2] * x[2] + x[3] * x[3];
#pragma unroll
    for (int off = 1; off < 64; off <<= 1) {
        s += __shfl_xor(s, off);
        q += __shfl_xor(q, off);
    }
    __shared__ float rs[4], rq[4];
    if (lane == 0) { rs[wave] = s; rq[wave] = q; }
    __syncthreads();
    s = rs[0] + rs[1] + rs[2] + rs[3];
    q = rq[0] + rq[1] + rq[2] + rq[3];
    const float mu = s * (1.f / 1024.f);
    const float var = q * (1.f / 1024.f) - mu * mu;
    const float rstd = rsqrtf(var + 1e-12f);
    f32x4 gv = *(const f32x4*)(gam + tid * 4);
    f32x4 bv = *(const f32x4*)(bet + tid * 4);
    f16x4 av, pv;
#pragma unroll
    for (int j = 0; j < 4; ++j) {
        const float y = (x[j] - mu) * rstd * gv[j] + bv[j];
        av[j] = (_Float16)y;
        pv[j] = (_Float16)x[j];
    }
    *(f16x4*)(ai + base) = av;
    *(f16x4*)(pn + base) = pv;
}

// final LN: out = LN(fuse) where fuse already = input_tensor + fusion
__global__ __launch_bounds__(256) void ln_out(
    const float* __restrict__ fuse, const float* __restrict__ gam,
    const float* __restrict__ bet, float* __restrict__ outp)
{
    const int n = blockIdx.x, tid = threadIdx.x;
    const int lane = tid & 63, wave = tid >> 6;
    const size_t base = (size_t)n * 1024 + tid * 4;
    f32x4 x = *(const f32x4*)(fuse + base);
    float s = x[0] + x[1] + x[2] + x[3];
    float q = x[0] * x[0] + x[1] * x[1] + x[2] * x[2] + x[3] * x[3];
#pragma unroll
    for (int off = 1; off < 64; off <<= 1) {
        s += __shfl_xor(s, off);
        q += __shfl_xor(q, off);
    }
    __shared__ float rs[4], rq[4];
    if (lane == 0) { rs[wave] = s; rq[wave] = q; }
    __syncthreads();
    s = rs[0] + rs[1] + rs[2] + rs[3];
    q = rq[0] + rq[1] + rq[2] + rq[3];
    const float mu = s * (1.f / 1024.f);
    const float var = q * (1.f / 1024.f) - mu * mu;
    const float rstd = rsqrtf(var + 1e-12f);
    f32x4 gv = *(const f32x4*)(gam + tid * 4);
    f32x4 bv = *(const f32x4*)(bet + tid * 4);
    f32x4 y;
#pragma unroll
    for (int j = 0; j < 4; ++j) y[j] = (x[j] - mu) * rstd * gv[j] + bv[j];
    *(f32x4*)(outp + base) = y;
}

// ---------------------------------------------------------------------------
// scores + softmax over T + weighted down (wdown = probs * down), per token.
// scores[t,n] = down[n,:]·g[n,:]|task t  +  qk[n,:]·up_b[t,:]  +  query[n,:]·key_b
// ---------------------------------------------------------------------------
__global__ __launch_bounds__(256) void scores_softmax(
    const _Float16* __restrict__ qk, const _Float16* __restrict__ query,
    const float* __restrict__ key_b, const float* __restrict__ up_b,
    const _Float16* __restrict__ down, const _Float16* __restrict__ g,
    float* __restrict__ probs_out, _Float16* __restrict__ wdown)
{
    const int n = blockIdx.x, tid = threadIdx.x;
    const int lane = tid & 63, wave = tid >> 6;
    const _Float16* qkrow = qk + (size_t)n * 1024;
    const _Float16* qrow  = query + (size_t)n * 1024;
    float ub[8] = {};
    float qb = 0.f;
#pragma unroll
    for (int j = 0; j < 4; ++j) {
        const int h = tid + j * 256;
        const float qkv = (float)qkrow[h];
        qb += (float)qrow[h] * key_b[h];
#pragma unroll
        for (int t = 0; t < 8; ++t) ub[t] += qkv * up_b[t * 1024 + h];
    }
#pragma unroll
    for (int off = 1; off < 64; off <<= 1) {
        qb += __shfl_xor(qb, off);
#pragma unroll
        for (int t = 0; t < 8; ++t) ub[t] += __shfl_xor(ub[t], off);
    }
    __shared__ float red[4][9];
    __shared__ float sd[8];
    __shared__ float pl[8];
    if (lane == 0) {
        red[wave][0] = qb;
#pragma unroll
        for (int t = 0; t < 8; ++t) red[wave][1 + t] = ub[t];
    }
    // per-task dot(down, g): c = 2*tid, 2*tid+1 both in task tid/32
    const int c0 = tid * 2;
    const size_t dbase = (size_t)n * 512;
    const float d0 = (float)down[dbase + c0];
    const float d1 = (float)down[dbase + c0 + 1];
    float pz = d0 * (float)g[dbase + c0] + d1 * (float)g[dbase + c0 + 1];
#pragma unroll
    for (int off = 1; off < 32; off <<= 1) pz += __shfl_xor(pz, off);
    if ((lane & 31) == 0) sd[wave * 2 + (lane >> 5)] = pz;
    __syncthreads();
    if (tid == 0) {
        const float qbt = red[0][0] + red[1][0] + red[2][0] + red[3][0];
        float sc[8];
        float mx = -1e30f;
#pragma unroll
        for (int t = 0; t < 8; ++t) {
            sc[t] = sd[t] + qbt + red[0][1 + t] + red[1][1 + t] + red[2][1 + t] + red[3][1 + t];
            mx = fmaxf(mx, sc[t]);
        }
        float sum = 0.f;
#pragma unroll
        for (int t = 0; t < 8; ++t) { sc[t] = expf(sc[t] - mx); sum += sc[t]; }
        const float inv = 1.f / sum;
#pragma unroll
        for (int t = 0; t < 8; ++t) pl[t] = sc[t] * inv;
    }
    __syncthreads();
    const float pr = pl[c0 >> 6];
    wdown[dbase + c0]     = (_Float16)(pr * d0);
    wdown[dbase + c0 + 1] = (_Float16)(pr * d1);
    if (tid < 8) probs_out[(size_t)n * 8 + tid] = pl[tid];
}

// ---------------------------------------------------------------------------
// conversions / layout prep
// ---------------------------------------------------------------------------
__device__ inline void cvt_seg(const float* __restrict__ s, _Float16* __restrict__ d,
                               int n4, int gid, int gsz)
{
    for (int i = gid; i < n4; i += gsz) {
        f32x4 v = ((const f32x4*)s)[i];
        f16x4 o;
        o[0] = (_Float16)v[0]; o[1] = (_Float16)v[1];
        o[2] = (_Float16)v[2]; o[3] = (_Float16)v[3];
        ((f16x4*)d)[i] = o;
    }
}

__global__ __launch_bounds__(256) void convert4(
    const float* s0, _Float16* d0, int n0,
    const float* s1, _Float16* d1, int n1,
    const float* s2, _Float16* d2, int n2,
    const float* s3, _Float16* d3, int n3)
{
    const int gid = blockIdx.x * 256 + threadIdx.x;
    const int gsz = gridDim.x * 256;
    cvt_seg(s0, d0, n0, gid, gsz);
    cvt_seg(s1, d1, n1, gid, gsz);
    cvt_seg(s2, d2, n2, gid, gsz);
    cvt_seg(s3, d3, n3, gid, gsz);
}

// key_w [k,h] -> w_keyT [h,k] (f16)
__global__ __launch_bounds__(256) void transpose_kw(
    const float* __restrict__ in, _Float16* __restrict__ outp)
{
    __shared__ float t[32][33];
    const int bx = blockIdx.x * 32;  // h block
    const int by = blockIdx.y * 32;  // k block
    const int tx = threadIdx.x & 31, ty = threadIdx.x >> 5;  // ty in 0..7
#pragma unroll
    for (int j = 0; j < 32; j += 8)
        t[ty + j][tx] = in[(size_t)(by + ty + j) * 1024 + bx + tx];
    __syncthreads();
#pragma unroll
    for (int j = 0; j < 32; j += 8)
        outp[(size_t)(bx + ty + j) * 1024 + by + tx] = (_Float16)t[tx][ty + j];
}

// up_w [t,h,d] -> w_upg[(t*64+d), h]  and  w_upmix[h, t*64+d]   (f16)
__global__ __launch_bounds__(256) void reshape_up(
    const float* __restrict__ up_w, _Float16* __restrict__ upg,
    _Float16* __restrict__ upmix)
{
    const int i = blockIdx.x * 256 + threadIdx.x;  // < 8*1024*64 = 524288
    const int d = i & 63;
    const int h = (i >> 6) & 1023;
    const int t = i >> 16;
    const float v = up_w[i];
    upg[(size_t)(t * 64 + d) * 1024 + h] = (_Float16)v;
    upmix[(size_t)h * 512 + t * 64 + d]  = (_Float16)v;
}

// ---------------------------------------------------------------------------
extern "C" void kernel_launch(void* const* d_in, const int* in_sizes, int n_in,
                              void* d_out, int out_size, void* d_ws, size_t ws_size,
                              hipStream_t stream)
{
    const float* hs      = (const float*)d_in[0];
    const float* it      = (const float*)d_in[1];
    const float* dense_w = (const float*)d_in[2];
    const float* dense_b = (const float*)d_in[3];
    const float* ln_g    = (const float*)d_in[4];
    const float* ln_b    = (const float*)d_in[5];
    const float* down_w  = (const float*)d_in[6];
    const float* down_b  = (const float*)d_in[7];
    const float* up_w    = (const float*)d_in[8];
    const float* up_b    = (const float*)d_in[9];
    const float* key_w   = (const float*)d_in[10];
    const float* key_b   = (const float*)d_in[11];
    const float* query_w = (const float*)d_in[12];
    const float* query_b = (const float*)d_in[13];
    const float* value_w = (const float*)d_in[14];
    float* outp = (float*)d_out;

    // workspace carve (~77 MB total)
    char* p = (char*)d_ws;
    _Float16* w_dense = (_Float16*)p;  p += (size_t)HID * IDIM * 2;
    _Float16* w_query = (_Float16*)p;  p += (size_t)HID * HID * 2;
    _Float16* w_keyT  = (_Float16*)p;  p += (size_t)HID * HID * 2;
    _Float16* w_value = (_Float16*)p;  p += (size_t)HID * HID * 2;
    _Float16* w_down  = (_Float16*)p;  p += (size_t)512 * HID * 2;
    _Float16* w_upg   = (_Float16*)p;  p += (size_t)512 * HID * 2;
    _Float16* w_upmix = (_Float16*)p;  p += (size_t)HID * 512 * 2;
    float*    h_f32   = (float*)p;     p += (size_t)TOK * HID * 4;
    _Float16* ai      = (_Float16*)p;  p += (size_t)TOK * HID * 2;   // adapter_in, reused as `mixed`
    _Float16* pn      = (_Float16*)p;                                 // prenorm f16
    float*    fuse    = (float*)p;     p += (size_t)TOK * HID * 2;   // fuse aliases [pn|query] (16 MB)
    _Float16* query   = (_Float16*)p;  p += (size_t)TOK * HID * 2;
    _Float16* qk      = (_Float16*)p;  p += (size_t)TOK * HID * 2;
    _Float16* down    = (_Float16*)p;  p += (size_t)TOK * 512 * 2;
    _Float16* g       = (_Float16*)p;  p += (size_t)TOK * 512 * 2;
    _Float16* wdown   = (_Float16*)p;  p += (size_t)TOK * 512 * 2;
    float*    probs   = (float*)p;     p += (size_t)TOK * 8 * 4;
    _Float16* mixed   = ai;
    (void)in_sizes; (void)n_in; (void)out_size; (void)ws_size;

    // weight prep
    convert4<<<1024, 256, 0, stream>>>(dense_w, w_dense, HID * IDIM / 4,
                                       query_w, w_query, HID * HID / 4,
                                       value_w, w_value, HID * HID / 4,
                                       down_w,  w_down,  512 * HID / 4);
    transpose_kw<<<dim3(32, 32), 256, 0, stream>>>(key_w, w_keyT);
    reshape_up<<<2048, 256, 0, stream>>>(up_w, w_upg, w_upmix);

    // h = hs @ dense_w^T + dense_b     (fp32 A converted in staging)
    gemm_nt<0, true><<<dim3(32, 8), 256, 0, stream>>>(
        hs, nullptr, w_dense, IDIM, HID, h_f32, nullptr, dense_b, nullptr, nullptr, nullptr);
    // adapter_in = LN(it + h), prenorm f16
    ln_adapter<<<TOK, 256, 0, stream>>>(h_f32, it, ln_g, ln_b, ai, pn);
    // query = prenorm @ query_w^T + query_b
    gemm_nt<1, false><<<dim3(32, 8), 256, 0, stream>>>(
        nullptr, pn, w_query, HID, HID, nullptr, query, query_b, nullptr, nullptr, nullptr);
    // qk = query @ key_w
    gemm_nt<1, false><<<dim3(32, 8), 256, 0, stream>>>(
        nullptr, query, w_keyT, HID, HID, nullptr, qk, nullptr, nullptr, nullptr, nullptr);
    // down = relu(adapter_in @ down_w^T + down_b)   [N, T*D]
    gemm_nt<2, false><<<dim3(32, 4), 256, 0, stream>>>(
        nullptr, ai, w_down, HID, 512, nullptr, down, down_b, nullptr, nullptr, nullptr);
    // g = qk @ up_w (per task)                      [N, T*D]
    gemm_nt<1, false><<<dim3(32, 4), 256, 0, stream>>>(
        nullptr, qk, w_upg, HID, 512, nullptr, g, nullptr, nullptr, nullptr, nullptr);
    // scores -> softmax over T -> probs, wdown = probs*down
    scores_softmax<<<TOK, 256, 0, stream>>>(qk, query, key_b, up_b, down, g, probs, wdown);
    // mixed = wdown @ up_w^T + probs@up_b + h
    gemm_nt<3, false><<<dim3(32, 8), 256, 0, stream>>>(
        nullptr, wdown, w_upmix, 512, HID, nullptr, mixed, nullptr, h_f32, probs, up_b);
    // fuse = mixed @ value_w^T + input_tensor
    gemm_nt<4, false><<<dim3(32, 8), 256, 0, stream>>>(
        nullptr, mixed, w_value, HID, HID, fuse, nullptr, nullptr, it, nullptr, nullptr);
    // out = LN(fuse)
    ln_out<<<TOK, 256, 0, stream>>>(fuse, ln_g, ln_b, outp);
}

// Round 2
// 401.079 us; speedup vs baseline: 1.2332x; 1.2332x over previous
//
#include <hip/hip_runtime.h>
#include <cstdint>
#include <cstddef>

typedef float   f32x4 __attribute__((ext_vector_type(4)));
typedef _Float16 f16x8 __attribute__((ext_vector_type(8)));
typedef _Float16 f16x4 __attribute__((ext_vector_type(4)));

#define TOK  4096   // B*S tokens
#define HID  1024
#define IDIM 4096
#define LDP  40     // padded LDS row stride in halfs (80 B): banks (row*20)%32 -> 2-way (free)

// ---------------------------------------------------------------------------
// Dense GEMM with split-K: partial[z] = A[Mx(K/SK)] * B^T, fp32 A cvt in staging.
// 128x128 tile, BK=32, 256 thr = 4 waves (2x2), wave 64x64 (4x4 MFMA).
// grid (M/128, N/128, SK). Writes fp32 partials (no bias).
// ---------------------------------------------------------------------------
__global__ __launch_bounds__(256, 4) void gemm_sk(
    const float* __restrict__ Af, const _Float16* __restrict__ B,
    int K, int Kchunk, float* __restrict__ part)
{
    __shared__ _Float16 lA[128 * LDP];
    __shared__ _Float16 lB[128 * LDP];
    const int tid  = threadIdx.x;
    const int lane = tid & 63;
    const int wave = tid >> 6;
    const int m0   = blockIdx.x * 128;
    const int n0   = blockIdx.y * 128;
    const int kz0  = blockIdx.z * Kchunk;
    const int wM   = (wave & 1) * 64;
    const int wN   = (wave >> 1) * 64;

    f32x4 acc[4][4] = {};

    for (int k0 = kz0; k0 < kz0 + Kchunk; k0 += 32) {
#pragma unroll
        for (int j = 0; j < 2; ++j) {
            const int q   = tid + j * 256;
            const int row = q >> 2;
            const int kc  = q & 3;
            const float* src = Af + (size_t)(m0 + row) * K + k0 + kc * 8;
            f32x4 v0 = *(const f32x4*)src;
            f32x4 v1 = *(const f32x4*)(src + 4);
            f16x8 o;
            o[0] = (_Float16)v0[0]; o[1] = (_Float16)v0[1];
            o[2] = (_Float16)v0[2]; o[3] = (_Float16)v0[3];
            o[4] = (_Float16)v1[0]; o[5] = (_Float16)v1[1];
            o[6] = (_Float16)v1[2]; o[7] = (_Float16)v1[3];
            *(f16x8*)(lA + row * LDP + kc * 8) = o;
            uint4 vb = *(const uint4*)(B + (size_t)(n0 + row) * K + k0 + kc * 8);
            *(uint4*)(lB + row * LDP + kc * 8) = vb;
        }
        __syncthreads();
        const int fr  = lane & 15;
        const int kc8 = (lane >> 4) * 8;
        f16x8 afr[4], bfr[4];
#pragma unroll
        for (int mi = 0; mi < 4; ++mi)
            afr[mi] = *(const f16x8*)(lA + (wM + mi * 16 + fr) * LDP + kc8);
#pragma unroll
        for (int ni = 0; ni < 4; ++ni)
            bfr[ni] = *(const f16x8*)(lB + (wN + ni * 16 + fr) * LDP + kc8);
#pragma unroll
        for (int mi = 0; mi < 4; ++mi)
#pragma unroll
            for (int ni = 0; ni < 4; ++ni)
                acc[mi][ni] = __builtin_amdgcn_mfma_f32_16x16x32_f16(
                    afr[mi], bfr[ni], acc[mi][ni], 0, 0, 0);
        __syncthreads();
    }

    float* dst = part + (size_t)blockIdx.z * TOK * HID;
    const int cn = lane & 15;
    const int rq = (lane >> 4) * 4;
#pragma unroll
    for (int mi = 0; mi < 4; ++mi)
#pragma unroll
        for (int r = 0; r < 4; ++r) {
            const int m = m0 + wM + mi * 16 + rq + r;
#pragma unroll
            for (int ni = 0; ni < 4; ++ni) {
                const int n = n0 + wN + ni * 16 + cn;
                dst[(size_t)m * HID + n] = acc[mi][ni][r];
            }
        }
}

// ---------------------------------------------------------------------------
// Small-K GEMM: 1024 thr = 16 waves (4x4), wave 32x32 (2x2 MFMA), 128x128 tile.
// MODE 1: outH = f16(acc + (bias?bias[n]:0))
// MODE 3: outH = f16(acc + addv + sum_t probs*up_b)
// MODE 4: outF = acc + addv
// MODE 5: dual N=512 GEMM: by<4 -> down=relu(Ah@B^T+bias); by>=4 -> g=A2@B2^T
// ---------------------------------------------------------------------------
template <int MODE>
__global__ __launch_bounds__(1024, 4) void gemm_w32(
    const _Float16* __restrict__ Ah, const _Float16* __restrict__ B,
    int K, int Ncols,
    float* __restrict__ outF, _Float16* __restrict__ outH,
    const float* __restrict__ bias, const float* __restrict__ addv,
    const float* __restrict__ probs, const float* __restrict__ upb,
    const _Float16* __restrict__ A2, const _Float16* __restrict__ B2,
    _Float16* __restrict__ outH2)
{
    __shared__ _Float16 lA[128 * LDP];
    __shared__ _Float16 lB[128 * LDP];
    const int tid  = threadIdx.x;
    const int lane = tid & 63;
    const int wave = tid >> 6;
    const int m0   = blockIdx.x * 128;
    int n0, half = 0;
    const _Float16* Ap = Ah;
    const _Float16* Bp = B;
    if constexpr (MODE == 5) {
        half = blockIdx.y >> 2;
        n0 = (blockIdx.y & 3) * 128;
        if (half) { Ap = A2; Bp = B2; }
    } else {
        n0 = blockIdx.y * 128;
    }
    const int wM = (wave & 3) * 32;
    const int wN = (wave >> 2) * 32;

    f32x4 acc[2][2] = {};

    const int st   = tid & 511;
    const int srow = st >> 2;
    const int sc   = (st & 3) * 8;
    const _Float16* sbase = (tid < 512)
        ? Ap + (size_t)(m0 + srow) * K + sc
        : Bp + (size_t)(n0 + srow) * K + sc;
    _Float16* sdst = ((tid < 512) ? lA : lB) + srow * LDP + sc;

    for (int k0 = 0; k0 < K; k0 += 32) {
        *(uint4*)sdst = *(const uint4*)(sbase + k0);
        __syncthreads();
        const int fr  = lane & 15;
        const int kc8 = (lane >> 4) * 8;
        f16x8 afr[2], bfr[2];
#pragma unroll
        for (int mi = 0; mi < 2; ++mi)
            afr[mi] = *(const f16x8*)(lA + (wM + mi * 16 + fr) * LDP + kc8);
#pragma unroll
        for (int ni = 0; ni < 2; ++ni)
            bfr[ni] = *(const f16x8*)(lB + (wN + ni * 16 + fr) * LDP + kc8);
#pragma unroll
        for (int mi = 0; mi < 2; ++mi)
#pragma unroll
            for (int ni = 0; ni < 2; ++ni)
                acc[mi][ni] = __builtin_amdgcn_mfma_f32_16x16x32_f16(
                    afr[mi], bfr[ni], acc[mi][ni], 0, 0, 0);
        __syncthreads();
    }

    const int cn = lane & 15;
    const int rq = (lane >> 4) * 4;
#pragma unroll
    for (int mi = 0; mi < 2; ++mi)
#pragma unroll
        for (int r = 0; r < 4; ++r) {
            const int m = m0 + wM + mi * 16 + rq + r;
#pragma unroll
            for (int ni = 0; ni < 2; ++ni) {
                const int n = n0 + wN + ni * 16 + cn;
                const float v = acc[mi][ni][r];
                if constexpr (MODE == 1) {
                    const float bb = bias ? bias[n] : 0.f;
                    outH[(size_t)m * Ncols + n] = (_Float16)(v + bb);
                } else if constexpr (MODE == 3) {
                    const size_t idx = (size_t)m * Ncols + n;
                    float s = v + addv[idx];
#pragma unroll
                    for (int t = 0; t < 8; ++t)
                        s += probs[(size_t)m * 8 + t] * upb[t * 1024 + n];
                    outH[idx] = (_Float16)s;
                } else if constexpr (MODE == 4) {
                    const size_t idx = (size_t)m * Ncols + n;
                    outF[idx] = v + addv[idx];
                } else {  // MODE 5
                    const size_t idx = (size_t)m * 512 + n;
                    if (half == 0) {
                        const float y = v + bias[n];
                        outH[idx] = (_Float16)(y > 0.f ? y : 0.f);
                    } else {
                        outH2[idx] = (_Float16)v;
                    }
                }
            }
        }
}

// ---------------------------------------------------------------------------
// fused split-K reduce + bias + LN: h = sum_z part[z] + dense_b;
// prenorm = h + it; ai = LN(prenorm); emits h_f32, ai(f16), pn(f16)
// ---------------------------------------------------------------------------
__global__ __launch_bounds__(256) void ln_fused(
    const float* __restrict__ part, int sk,
    const float* __restrict__ dbias, const float* __restrict__ it,
    const float* __restrict__ gam, const float* __restrict__ bet,
    float* __restrict__ h_f32, _Float16* __restrict__ ai, _Float16* __restrict__ pn)
{
    const int n = blockIdx.x, tid = threadIdx.x;
    const int lane = tid & 63, wave = tid >> 6;
    const size_t base = (size_t)n * 1024 + tid * 4;
    f32x4 h = *(const f32x4*)(dbias + tid * 4);
    for (int z = 0; z < sk; ++z)
        h += *(const f32x4*)(part + (size_t)z * TOK * HID + base);
    *(f32x4*)(h_f32 + base) = h;
    f32x4 x = h + *(const f32x4*)(it + base);
    float s = x[0] + x[1] + x[2] + x[3];
    float q = x[0] * x[0] + x[1] * x[1] + x[2] * x[2] + x[3] * x[3];
#pragma unroll
    for (int off = 1; off < 64; off <<= 1) {
        s += __shfl_xor(s, off);
        q += __shfl_xor(q, off);
    }
    __shared__ float rs[4], rq[4];
    if (lane == 0) { rs[wave] = s; rq[wave] = q; }
    __syncthreads();
    s = rs[0] + rs[1] + rs[2] + rs[3];
    q = rq[0] + rq[1] + rq[2] + rq[3];
    const float mu = s * (1.f / 1024.f);
    const float var = q * (1.f / 1024.f) - mu * mu;
    const float rstd = rsqrtf(var + 1e-12f);
    f32x4 gv = *(const f32x4*)(gam + tid * 4);
    f32x4 bv = *(const f32x4*)(bet + tid * 4);
    f16x4 av, pv;
#pragma unroll
    for (int j = 0; j < 4; ++j) {
        const float y = (x[j] - mu) * rstd * gv[j] + bv[j];
        av[j] = (_Float16)y;
        pv[j] = (_Float16)x[j];
    }
    *(f16x4*)(ai + base) = av;
    *(f16x4*)(pn + base) = pv;
}

// final LN: out = LN(fuse) where fuse already = input_tensor + fusion
__global__ __launch_bounds__(256) void ln_out(
    const float* __restrict__ fuse, const float* __restrict__ gam,
    const float* __restrict__ bet, float* __restrict__ outp)
{
    const int n = blockIdx.x, tid = threadIdx.x;
    const int lane = tid & 63, wave = tid >> 6;
    const size_t base = (size_t)n * 1024 + tid * 4;
    f32x4 x = *(const f32x4*)(fuse + base);
    float s = x[0] + x[1] + x[2] + x[3];
    float q = x[0] * x[0] + x[1] * x[1] + x[2] * x[2] + x[3] * x[3];
#pragma unroll
    for (int off = 1; off < 64; off <<= 1) {
        s += __shfl_xor(s, off);
        q += __shfl_xor(q, off);
    }
    __shared__ float rs[4], rq[4];
    if (lane == 0) { rs[wave] = s; rq[wave] = q; }
    __syncthreads();
    s = rs[0] + rs[1] + rs[2] + rs[3];
    q = rq[0] + rq[1] + rq[2] + rq[3];
    const float mu = s * (1.f / 1024.f);
    const float var = q * (1.f / 1024.f) - mu * mu;
    const float rstd = rsqrtf(var + 1e-12f);
    f32x4 gv = *(const f32x4*)(gam + tid * 4);
    f32x4 bv = *(const f32x4*)(bet + tid * 4);
    f32x4 y;
#pragma unroll
    for (int j = 0; j < 4; ++j) y[j] = (x[j] - mu) * rstd * gv[j] + bv[j];
    *(f32x4*)(outp + base) = y;
}

// ---------------------------------------------------------------------------
// scores + softmax over T + wdown = probs * down, per token.
// ---------------------------------------------------------------------------
__global__ __launch_bounds__(256) void scores_softmax(
    const _Float16* __restrict__ qk, const _Float16* __restrict__ query,
    const float* __restrict__ key_b, const float* __restrict__ up_b,
    const _Float16* __restrict__ down, const _Float16* __restrict__ g,
    float* __restrict__ probs_out, _Float16* __restrict__ wdown)
{
    const int n = blockIdx.x, tid = threadIdx.x;
    const int lane = tid & 63, wave = tid >> 6;
    const _Float16* qkrow = qk + (size_t)n * 1024;
    const _Float16* qrow  = query + (size_t)n * 1024;
    float ub[8] = {};
    float qb = 0.f;
#pragma unroll
    for (int j = 0; j < 4; ++j) {
        const int h = tid + j * 256;
        const float qkv = (float)qkrow[h];
        qb += (float)qrow[h] * key_b[h];
#pragma unroll
        for (int t = 0; t < 8; ++t) ub[t] += qkv * up_b[t * 1024 + h];
    }
#pragma unroll
    for (int off = 1; off < 64; off <<= 1) {
        qb += __shfl_xor(qb, off);
#pragma unroll
        for (int t = 0; t < 8; ++t) ub[t] += __shfl_xor(ub[t], off);
    }
    __shared__ float red[4][9];
    __shared__ float sd[8];
    __shared__ float pl[8];
    if (lane == 0) {
        red[wave][0] = qb;
#pragma unroll
        for (int t = 0; t < 8; ++t) red[wave][1 + t] = ub[t];
    }
    const int c0 = tid * 2;
    const size_t dbase = (size_t)n * 512;
    const float d0 = (float)down[dbase + c0];
    const float d1 = (float)down[dbase + c0 + 1];
    float pz = d0 * (float)g[dbase + c0] + d1 * (float)g[dbase + c0 + 1];
#pragma unroll
    for (int off = 1; off < 32; off <<= 1) pz += __shfl_xor(pz, off);
    if ((lane & 31) == 0) sd[wave * 2 + (lane >> 5)] = pz;
    __syncthreads();
    if (tid == 0) {
        const float qbt = red[0][0] + red[1][0] + red[2][0] + red[3][0];
        float sc[8];
        float mx = -1e30f;
#pragma unroll
        for (int t = 0; t < 8; ++t) {
            sc[t] = sd[t] + qbt + red[0][1 + t] + red[1][1 + t] + red[2][1 + t] + red[3][1 + t];
            mx = fmaxf(mx, sc[t]);
        }
        float sum = 0.f;
#pragma unroll
        for (int t = 0; t < 8; ++t) { sc[t] = expf(sc[t] - mx); sum += sc[t]; }
        const float inv = 1.f / sum;
#pragma unroll
        for (int t = 0; t < 8; ++t) pl[t] = sc[t] * inv;
    }
    __syncthreads();
    const float pr = pl[c0 >> 6];
    wdown[dbase + c0]     = (_Float16)(pr * d0);
    wdown[dbase + c0 + 1] = (_Float16)(pr * d1);
    if (tid < 8) probs_out[(size_t)n * 8 + tid] = pl[tid];
}

// ---------------------------------------------------------------------------
// conversions / layout prep
// ---------------------------------------------------------------------------
__device__ inline void cvt_seg(const float* __restrict__ s, _Float16* __restrict__ d,
                               int n4, int gid, int gsz)
{
    for (int i = gid; i < n4; i += gsz) {
        f32x4 v = ((const f32x4*)s)[i];
        f16x4 o;
        o[0] = (_Float16)v[0]; o[1] = (_Float16)v[1];
        o[2] = (_Float16)v[2]; o[3] = (_Float16)v[3];
        ((f16x4*)d)[i] = o;
    }
}

__global__ __launch_bounds__(256) void convert4(
    const float* s0, _Float16* d0, int n0,
    const float* s1, _Float16* d1, int n1,
    const float* s2, _Float16* d2, int n2,
    const float* s3, _Float16* d3, int n3)
{
    const int gid = blockIdx.x * 256 + threadIdx.x;
    const int gsz = gridDim.x * 256;
    cvt_seg(s0, d0, n0, gid, gsz);
    cvt_seg(s1, d1, n1, gid, gsz);
    cvt_seg(s2, d2, n2, gid, gsz);
    cvt_seg(s3, d3, n3, gid, gsz);
}

// key_w [k,h] -> w_keyT [h,k] (f16)
__global__ __launch_bounds__(256) void transpose_kw(
    const float* __restrict__ in, _Float16* __restrict__ outp)
{
    __shared__ float t[32][33];
    const int bx = blockIdx.x * 32;
    const int by = blockIdx.y * 32;
    const int tx = threadIdx.x & 31, ty = threadIdx.x >> 5;
#pragma unroll
    for (int j = 0; j < 32; j += 8)
        t[ty + j][tx] = in[(size_t)(by + ty + j) * 1024 + bx + tx];
    __syncthreads();
#pragma unroll
    for (int j = 0; j < 32; j += 8)
        outp[(size_t)(bx + ty + j) * 1024 + by + tx] = (_Float16)t[tx][ty + j];
}

// up_w [t,h,d] -> w_upg[(t*64+d), h]  and  w_upmix[h, t*64+d]   (f16)
__global__ __launch_bounds__(256) void reshape_up(
    const float* __restrict__ up_w, _Float16* __restrict__ upg,
    _Float16* __restrict__ upmix)
{
    const int i = blockIdx.x * 256 + threadIdx.x;
    const int d = i & 63;
    const int h = (i >> 6) & 1023;
    const int t = i >> 16;
    const float v = up_w[i];
    upg[(size_t)(t * 64 + d) * 1024 + h] = (_Float16)v;
    upmix[(size_t)h * 512 + t * 64 + d]  = (_Float16)v;
}

// ---------------------------------------------------------------------------
extern "C" void kernel_launch(void* const* d_in, const int* in_sizes, int n_in,
                              void* d_out, int out_size, void* d_ws, size_t ws_size,
                              hipStream_t stream)
{
    const float* hs      = (const float*)d_in[0];
    const float* it      = (const float*)d_in[1];
    const float* dense_w = (const float*)d_in[2];
    const float* dense_b = (const float*)d_in[3];
    const float* ln_g    = (const float*)d_in[4];
    const float* ln_b    = (const float*)d_in[5];
    const float* down_w  = (const float*)d_in[6];
    const float* down_b  = (const float*)d_in[7];
    const float* up_w    = (const float*)d_in[8];
    const float* up_b    = (const float*)d_in[9];
    const float* key_w   = (const float*)d_in[10];
    const float* key_b   = (const float*)d_in[11];
    const float* query_w = (const float*)d_in[12];
    const float* query_b = (const float*)d_in[13];
    const float* value_w = (const float*)d_in[14];
    float* outp = (float*)d_out;
    (void)in_sizes; (void)n_in; (void)out_size;

    const size_t MiB = 1ull << 20;
    // persistent region (49 MiB)
    char* p = (char*)d_ws;
    _Float16* w_dense = (_Float16*)p;  p += 8 * MiB;
    _Float16* w_query = (_Float16*)p;  p += 2 * MiB;
    _Float16* w_keyT  = (_Float16*)p;  p += 2 * MiB;
    _Float16* w_value = (_Float16*)p;  p += 2 * MiB;
    _Float16* w_down  = (_Float16*)p;  p += 1 * MiB;
    _Float16* w_upg   = (_Float16*)p;  p += 1 * MiB;
    _Float16* w_upmix = (_Float16*)p;  p += 1 * MiB;
    float*    h_f32   = (float*)p;     p += 16 * MiB;
    _Float16* ai      = (_Float16*)p;  p += 8 * MiB;   // reused as `mixed`
    _Float16* pn      = (_Float16*)p;  p += 8 * MiB;
    // region B: split-K partials first, then (aliased) activations
    char* rb = p;
    const int sk = (ws_size >= (size_t)(49 + 64) * MiB) ? 4 : 2;
    float*    part  = (float*)rb;                 // sk * 16 MiB
    _Float16* query = (_Float16*)rb;              // 8 MiB
    _Float16* qk    = (_Float16*)(rb +  8 * MiB); // 8 MiB
    _Float16* down  = (_Float16*)(rb + 16 * MiB); // 4 MiB
    _Float16* g     = (_Float16*)(rb + 20 * MiB); // 4 MiB
    _Float16* wdown = (_Float16*)(rb + 24 * MiB); // 4 MiB
    float*    probs = (float*)(rb + 28 * MiB);    // 128 KiB
    float*    fuse  = (float*)rb;                 // 16 MiB, aliases query+qk (dead)
    _Float16* mixed = ai;

    // weight prep
    convert4<<<1024, 256, 0, stream>>>(dense_w, w_dense, HID * IDIM / 4,
                                       query_w, w_query, HID * HID / 4,
                                       value_w, w_value, HID * HID / 4,
                                       down_w,  w_down,  512 * HID / 4);
    transpose_kw<<<dim3(32, 32), 256, 0, stream>>>(key_w, w_keyT);
    reshape_up<<<2048, 256, 0, stream>>>(up_w, w_upg, w_upmix);

    // dense partials: part[z] = hs @ dense_w^T  (K chunk per z)
    gemm_sk<<<dim3(32, 8, sk), 256, 0, stream>>>(hs, w_dense, IDIM, IDIM / sk, part);
    // h = sum partials + dense_b; ai = LN(h + it); pn = f16(h + it)
    ln_fused<<<TOK, 256, 0, stream>>>(part, sk, dense_b, it, ln_g, ln_b, h_f32, ai, pn);
    // query = pn @ query_w^T + query_b
    gemm_w32<1><<<dim3(32, 8), 1024, 0, stream>>>(
        pn, w_query, HID, HID, nullptr, query, query_b, nullptr, nullptr, nullptr,
        nullptr, nullptr, nullptr);
    // qk = query @ key_w
    gemm_w32<1><<<dim3(32, 8), 1024, 0, stream>>>(
        query, w_keyT, HID, HID, nullptr, qk, nullptr, nullptr, nullptr, nullptr,
        nullptr, nullptr, nullptr);
    // dual: down = relu(ai @ w_down^T + down_b);  g = qk @ w_upg^T
    gemm_w32<5><<<dim3(32, 8), 1024, 0, stream>>>(
        ai, w_down, HID, 512, nullptr, down, down_b, nullptr, nullptr, nullptr,
        qk, w_upg, g);
    // scores -> softmax over T -> probs, wdown = probs*down
    scores_softmax<<<TOK, 256, 0, stream>>>(qk, query, key_b, up_b, down, g, probs, wdown);
    // mixed = wdown @ up_w^T + probs@up_b + h
    gemm_w32<3><<<dim3(32, 8), 1024, 0, stream>>>(
        wdown, w_upmix, 512, HID, nullptr, mixed, nullptr, h_f32, probs, up_b,
        nullptr, nullptr, nullptr);
    // fuse = mixed @ value_w^T + input_tensor
    gemm_w32<4><<<dim3(32, 8), 1024, 0, stream>>>(
        mixed, w_value, HID, HID, fuse, nullptr, nullptr, it, nullptr, nullptr,
        nullptr, nullptr, nullptr);
    // out = LN(fuse)
    ln_out<<<TOK, 256, 0, stream>>>(fuse, ln_g, ln_b, outp);
}